// Round 5
// baseline (35.343 us; speedup 1.0000x reference)
//
#include <hip/hip_runtime.h>
#include <math.h>

#define NKP 68
#define NB 16
#define SK_ITERS 50

#define INVV 0.03125f                  // 1/(2*sigma^2), sigma=4
#define LOG_A (-4.219507705176107f)    // -log(68)
#define L2E 1.4426950408889634f
#define LN2 0.6931471805599453f
#define KGF (100.0f * L2E)             // (1/eps)*log2(e)
#define SW 40.0f                       // power-of-two shift baked into W
#define C2X (-INVV * 1.4426950408889634f)  // gaussian exponent, base-2

// workspace float offsets (all plain stores, no init needed)
#define WS_COST 0     // [16]   sinkhorn per-batch cost
#define WS_BCE0 16    // [1024] per-block bce partial sums

__device__ __forceinline__ float E2(float x) {
#if __has_builtin(__builtin_amdgcn_exp2f)
  return __builtin_amdgcn_exp2f(x);
#else
  return exp2f(x);
#endif
}
__device__ __forceinline__ float L2(float x) {
#if __has_builtin(__builtin_amdgcn_logf)
  return __builtin_amdgcn_logf(x);   // v_log_f32 = log2
#else
  return log2f(x);
#endif
}
__device__ __forceinline__ float RCP(float x) {
#if __has_builtin(__builtin_amdgcn_rcpf)
  return __builtin_amdgcn_rcpf(x);   // v_rcp_f32, ~1 ulp
#else
  return 1.0f / x;
#endif
}
// sum over lane pair (DPP quad_perm xor1) — both lanes get the total
__device__ __forceinline__ float dpp_xor1_add(float s) {
#if __has_builtin(__builtin_amdgcn_mov_dpp)
  int t = __builtin_amdgcn_mov_dpp(__float_as_int(s), 0xB1, 0xF, 0xF, true);
  return s + __int_as_float(t);
#else
  return s + __shfl_xor(s, 1);
#endif
}

// ---------------------------------------------------------------------------
// Sinkhorn in SCALING form: u = 2^40 / (W v), v = 2^40 / (W^T u), where
// W_ij = 2^40 e^{-C_ij/eps} / N is precomputed per lane (NO spill: only
// Wf[34]+Wg[34] arrays live across the loop; cost weights recomputed in the
// epilogue from log2(Wf)). 2 lanes per row, 136 active lanes in 3 waves.
// ---------------------------------------------------------------------------
__device__ void sink_part(const float* __restrict__ pred,
                          const float* __restrict__ targ,
                          float* __restrict__ ws, int b) {
  __shared__ float ush[80], vsh[80], wred[3];
  const int tid = threadIdx.x;
  const bool act = tid < 136;
  const int r = tid >> 1, q = tid & 1;
  const int rb = q * 40;               // LDS read base (16B aligned, padded groups of 40)

  float Wf[34], Wg[34];
  int wofs = 0;
  if (act) {
    const float2* pc = (const float2*)(pred + b * NKP * 2);
    const float2* tc = (const float2*)(targ + b * NKP * 2);
    const float2 xi = pc[r];   // pred point, f-row r
    const float2 yj = tc[r];   // targ point, g-row r
#pragma unroll
    for (int k = 0; k < 34; ++k) {
      const int j = q * 34 + k;
      float2 y = tc[j];
      float d0 = xi.x - y.x, d1 = xi.y - y.y;
      float c = d0 * d0 + d1 * d1;
      Wf[k] = E2(fmaf(-KGF, c, L2E * LOG_A + SW));
      float2 x2 = pc[j];
      d0 = x2.x - yj.x; d1 = x2.y - yj.y;
      float c2 = d0 * d0 + d1 * d1;
      Wg[k] = E2(fmaf(-KGF, c2, L2E * LOG_A + SW));
    }
    wofs = (r < 34) ? r : r + 6;       // padded write offset
  }
  if (tid < 80) vsh[tid] = 1.0f;       // v0 = exp(g0/eps) = 1
  __syncthreads();

#define LOAD34(DST, SRC)                                                     \
  {                                                                          \
    const float4* gv = (const float4*)&SRC[rb];                              \
    *(float4*)&DST[0]  = gv[0];                                              \
    *(float4*)&DST[4]  = gv[1];                                              \
    *(float4*)&DST[8]  = gv[2];                                              \
    *(float4*)&DST[12] = gv[3];                                              \
    *(float4*)&DST[16] = gv[4];                                              \
    *(float4*)&DST[20] = gv[5];                                              \
    *(float4*)&DST[24] = gv[6];                                              \
    *(float4*)&DST[28] = gv[7];                                              \
    *(float2*)&DST[32] = *(const float2*)&SRC[rb + 32];                      \
  }

#define SINK_HALF(SRC, DST, W, RESULT)                                       \
  {                                                                          \
    float s0 = 0, s1 = 0, s2 = 0, s3 = 0;                                    \
    if (act) {                                                               \
      float gl[34];                                                          \
      LOAD34(gl, SRC)                                                        \
      _Pragma("unroll")                                                      \
      for (int k = 0; k < 34; ++k) {                                         \
        float t = W[k] * gl[k];                                              \
        if ((k & 3) == 0) s0 += t;                                           \
        else if ((k & 3) == 1) s1 += t;                                      \
        else if ((k & 3) == 2) s2 += t;                                      \
        else s3 += t;                                                        \
      }                                                                      \
    }                                                                        \
    float s = (s0 + s1) + (s2 + s3);                                         \
    s = dpp_xor1_add(s);                                                     \
    RESULT = RCP(s) * 0x1p+40f;                                              \
    if (act && q == 0) DST[wofs] = RESULT;                                   \
  }

  float u = 0.0f, v = 0.0f;
#pragma unroll 1
  for (int it = 0; it < SK_ITERS; ++it) {
    SINK_HALF(vsh, ush, Wf, u)   // f-half: u = 2^40 / (W v)
    __syncthreads();
    SINK_HALF(ush, vsh, Wg, v)   // g-half: v = 2^40 / (W^T u)
    __syncthreads();
  }
  (void)v;

  // transport cost: cost_b = 2^-40/N * sum_i u_i * sum_j (W_ij C_ij) v_j
  // C_ij recomputed from log2(Wf): C = (L2E*LOG_A + SW - log2 Wf)/KGF,
  // guarded so underflowed W (=0) contributes exactly 0 (not NaN).
  float local = 0.0f;
  if (act) {
    float gl[34];
    LOAD34(gl, vsh)
    float c0 = 0, c1 = 0, c2 = 0, c3 = 0;
#pragma unroll
    for (int k = 0; k < 34; ++k) {
      float w = Wf[k];
      float cij = (L2E * LOG_A + SW - L2(w)) * (1.0f / KGF);
      float t = (w > 0.0f) ? w * cij * gl[k] : 0.0f;
      if ((k & 3) == 0) c0 += t;
      else if ((k & 3) == 1) c1 += t;
      else if ((k & 3) == 2) c2 += t;
      else c3 += t;
    }
    float sc = (c0 + c1) + (c2 + c3);
    sc = dpp_xor1_add(sc);
    if (q == 0) local = sc * u;
  }
  for (int o = 32; o; o >>= 1) local += __shfl_down(local, o);
  if ((tid & 63) == 0) wred[tid >> 6] = local;
  __syncthreads();
  if (tid == 0)
    ws[WS_COST + b] = (wred[0] + wred[1] + wred[2]) * (0x1p-40f / 68.0f);
}

// ---------------------------------------------------------------------------
// BCE: block = one batch x 8-row y-tile x 128-col x-half. Windowed (40-sample)
// per-axis gaussian sums for normalization; gy staged in LDS; gx recomputed.
// ---------------------------------------------------------------------------
__device__ void bce_part(const float* __restrict__ pred,
                         const float* __restrict__ targ,
                         float* __restrict__ ws, int bidx) {
  __shared__ float ls[4][NKP];
  __shared__ __attribute__((aligned(16))) float gyp8[NKP][8];
  __shared__ __attribute__((aligned(16))) float gyt8[NKP][8];
  __shared__ float pxp_s[NKP], pxt_s[NKP];
  __shared__ float sS[2];
  __shared__ float bred[3];

  const int b = bidx >> 6;
  const int t6 = bidx & 63;
  const int y0 = (t6 >> 1) * 8;
  const int xbase = (t6 & 1) * 128;
  const int tid = threadIdx.x;

  // phase 1a: windowed per-(n,axis) gaussian sums (tail < 2e-5 absolute)
  for (int idx = tid; idx < 272; idx += 192) {
    const int n = idx >> 2, slot = idx & 3;          // 0 px,1 py,2 tx,3 ty
    const float* src = (slot < 2) ? pred : targ;
    const float c = src[(b * NKP + n) * 2 + (slot & 1)] * 255.0f;
    int x0 = (int)c - 19;
    x0 = max(0, min(216, x0));
    float g0 = (float)x0 - c, g1 = g0 + 1.0f, g2 = g0 + 2.0f, g3 = g0 + 3.0f;
    float s0 = 0, s1 = 0, s2 = 0, s3 = 0;
#pragma unroll 2
    for (int v = 0; v < 10; ++v) {
      s0 += E2(g0 * g0 * C2X);
      s1 += E2(g1 * g1 * C2X);
      s2 += E2(g2 * g2 * C2X);
      s3 += E2(g3 * g3 * C2X);
      g0 += 4.0f; g1 += 4.0f; g2 += 4.0f; g3 += 4.0f;
    }
    ls[slot][n] = (s0 + s1) + (s2 + s3);
  }
  // phase 1b: stage x-centers and gy tiles
  for (int idx = tid; idx < NKP * 2; idx += 192) {
    const int n = idx >> 1, tsel = idx & 1;
    const float* c = tsel ? targ : pred;
    float v = c[(b * NKP + n) * 2] * 255.0f;
    (tsel ? pxt_s : pxp_s)[n] = v;
  }
  for (int idx = tid; idx < NKP * 16; idx += 192) {
    const int t2 = idx & 1, rr = (idx >> 1) & 7, n = idx >> 4;
    const float* c = t2 ? targ : pred;
    float py = c[(b * NKP + n) * 2 + 1] * 255.0f;
    float dy = (float)(y0 + rr) - py;
    (t2 ? gyt8 : gyp8)[n][rr] = E2(dy * dy * C2X);
  }
  __syncthreads();

  // reduce ls -> S_p, S_t
  if (tid < 64) {
    float sp = ls[0][tid] * ls[1][tid];
    float st = ls[2][tid] * ls[3][tid];
    if (tid < 4) {
      sp += ls[0][64 + tid] * ls[1][64 + tid];
      st += ls[2][64 + tid] * ls[3][64 + tid];
    }
    for (int o = 32; o; o >>= 1) { sp += __shfl_down(sp, o); st += __shfl_down(st, o); }
    if (tid == 0) { sS[0] = sp; sS[1] = st; }
  }
  __syncthreads();

  // phase 2: heatmap accumulation over keypoints (128 x-threads)
  float accp[8] = {0, 0, 0, 0, 0, 0, 0, 0};
  float acct[8] = {0, 0, 0, 0, 0, 0, 0, 0};
  if (tid < 128) {
    const float fx = (float)(xbase + tid);
    for (int n = 0; n < NKP; ++n) {
      float dxp = fx - pxp_s[n];
      float gxp = E2(dxp * dxp * C2X);
      float dxt = fx - pxt_s[n];
      float gxt = E2(dxt * dxt * C2X);
      const float4 gp0 = *(const float4*)&gyp8[n][0];
      const float4 gp1 = *(const float4*)&gyp8[n][4];
      const float4 gt0 = *(const float4*)&gyt8[n][0];
      const float4 gt1 = *(const float4*)&gyt8[n][4];
      accp[0] = fmaf(gp0.x, gxp, accp[0]);
      accp[1] = fmaf(gp0.y, gxp, accp[1]);
      accp[2] = fmaf(gp0.z, gxp, accp[2]);
      accp[3] = fmaf(gp0.w, gxp, accp[3]);
      accp[4] = fmaf(gp1.x, gxp, accp[4]);
      accp[5] = fmaf(gp1.y, gxp, accp[5]);
      accp[6] = fmaf(gp1.z, gxp, accp[6]);
      accp[7] = fmaf(gp1.w, gxp, accp[7]);
      acct[0] = fmaf(gt0.x, gxt, acct[0]);
      acct[1] = fmaf(gt0.y, gxt, acct[1]);
      acct[2] = fmaf(gt0.z, gxt, acct[2]);
      acct[3] = fmaf(gt0.w, gxt, acct[3]);
      acct[4] = fmaf(gt1.x, gxt, acct[4]);
      acct[5] = fmaf(gt1.y, gxt, acct[5]);
      acct[6] = fmaf(gt1.z, gxt, acct[6]);
      acct[7] = fmaf(gt1.w, gxt, acct[7]);
    }
  }

  // phase 3: bce terms (hardware v_log_f32; L2(0)=-inf -> clamp -100 matches ref)
  float local = 0.0f;
  if (tid < 128) {
    const float rsp = 1.0f / (sS[0] + 1e-8f);
    const float rst = 1.0f / sS[1];
#pragma unroll
    for (int rr = 0; rr < 8; ++rr) {
      float p = accp[rr] * rsp;
      float t = acct[rr] * rst;
      float lp = fmaxf(LN2 * L2(p), -100.0f);
      float l1 = fmaxf(LN2 * L2(1.0f - p), -100.0f);
      local += t * lp + (1.0f - t) * l1;
    }
  }
  for (int o = 32; o; o >>= 1) local += __shfl_down(local, o);
  if ((tid & 63) == 0) bred[tid >> 6] = local;
  __syncthreads();
  if (tid == 0)
    ws[WS_BCE0 + bidx] = bred[0] + bred[1] + bred[2];   // plain store
}

// ---------------------------------------------------------------------------
// Fused main kernel: blocks 0..15 sinkhorn, 16..1039 BCE.
// __launch_bounds__(192, 3): cap VGPR ~170 so sink_part's W arrays stay in
// registers (round-4 spill at VGPR=88 was the bottleneck) while keeping
// 3 waves/SIMD for the BCE blocks.
// ---------------------------------------------------------------------------
__global__ __launch_bounds__(192, 3) void k_main(const float* __restrict__ pred,
                                                 const float* __restrict__ targ,
                                                 float* __restrict__ ws) {
  if (blockIdx.x < 16)
    sink_part(pred, targ, ws, blockIdx.x);
  else
    bce_part(pred, targ, ws, blockIdx.x - 16);
}

// ---------------------------------------------------------------------------
// Final combine: reduce 1024 bce partials + 16 costs
// ---------------------------------------------------------------------------
__global__ __launch_bounds__(256) void k_final(const float* __restrict__ ws,
                                               float* __restrict__ out) {
  const int tid = threadIdx.x;
  __shared__ float redb[4], redc[4];
  float vb = 0.0f;
#pragma unroll
  for (int i = 0; i < 4; ++i) vb += ws[WS_BCE0 + tid + 256 * i];
  float vc = (tid < NB) ? ws[WS_COST + tid] : 0.0f;
  for (int o = 32; o; o >>= 1) { vb += __shfl_down(vb, o); vc += __shfl_down(vc, o); }
  if ((tid & 63) == 0) { redb[tid >> 6] = vb; redc[tid >> 6] = vc; }
  __syncthreads();
  if (tid == 0) {
    float B = redb[0] + redb[1] + redb[2] + redb[3];
    float C = redc[0] + redc[1] + redc[2] + redc[3];
    out[0] = -B * (1000000.0f / 1048576.0f) + C * (2000.0f / 16.0f);
  }
}

extern "C" void kernel_launch(void* const* d_in, const int* in_sizes, int n_in,
                              void* d_out, int out_size, void* d_ws, size_t ws_size,
                              hipStream_t stream) {
  const float* pred = (const float*)d_in[0];
  const float* targ = (const float*)d_in[1];
  float* ws = (float*)d_ws;
  float* out = (float*)d_out;

  k_main<<<16 + NB * 64, 192, 0, stream>>>(pred, targ, ws);
  k_final<<<1, 256, 0, stream>>>(ws, out);
}

// Round 7
// 29.204 us; speedup vs baseline: 1.2102x; 1.2102x over previous
//
#include <hip/hip_runtime.h>
#include <math.h>

#define NKP 68
#define NB 16
#define SK_ITERS 50

#define INVV 0.03125f                  // 1/(2*sigma^2), sigma=4
#define LOG_A (-4.219507705176107f)    // -log(68)
#define L2E 1.4426950408889634f
#define LN2 0.6931471805599453f
#define KGF (100.0f * L2E)             // (1/eps)*log2(e)
#define SW 40.0f                       // power-of-two shift baked into W
#define WBIAS (L2E * LOG_A + SW)
#define C2X (-INVV * 1.4426950408889634f)  // gaussian exponent, base-2

// workspace float offsets (all plain stores, no init needed)
#define WS_COST 0     // [16]   sinkhorn per-batch cost
#define WS_BCE0 16    // [1024] per-block bce partial sums

__device__ __forceinline__ float E2(float x) {
#if __has_builtin(__builtin_amdgcn_exp2f)
  return __builtin_amdgcn_exp2f(x);
#else
  return exp2f(x);
#endif
}
__device__ __forceinline__ float L2(float x) {
#if __has_builtin(__builtin_amdgcn_logf)
  return __builtin_amdgcn_logf(x);   // v_log_f32 = log2
#else
  return log2f(x);
#endif
}
__device__ __forceinline__ float RCP(float x) {
#if __has_builtin(__builtin_amdgcn_rcpf)
  return __builtin_amdgcn_rcpf(x);   // v_rcp_f32, ~1 ulp
#else
  return 1.0f / x;
#endif
}
// sum over lane pair (DPP quad_perm xor1) — both lanes get the total
__device__ __forceinline__ float dpp_xor1_add(float s) {
#if __has_builtin(__builtin_amdgcn_mov_dpp)
  int t = __builtin_amdgcn_mov_dpp(__float_as_int(s), 0xB1, 0xF, 0xF, true);
  return s + __int_as_float(t);
#else
  return s + __shfl_xor(s, 1);
#endif
}
// W_ij = 2^40 * exp(-C_ij/eps)/N, computed in base 2
__device__ __forceinline__ float wcomp(float2 a, float2 b) {
  float d0 = a.x - b.x, d1 = a.y - b.y;
  return E2(fmaf(-KGF, d0 * d0 + d1 * d1, WBIAS));
}

// token-paste helper so member access stays outside the paste
// (WP##8.x fails: "8.x" lexes as one pp-number token)
#define WREG(WP, N) WP##N

// ---------------------------------------------------------------------------
// Sinkhorn in SCALING form: u = 2^40 / (W v), v = 2^40 / (W^T u).
// W held in EXPLICIT named float4 registers (no local arrays -> no alloca ->
// no scratch; rounds 3-5 all silently spilled W via failed SROA).
// 2 lanes per row, 136 active lanes in 3 waves.
// ---------------------------------------------------------------------------
__device__ void sink_part(const float* __restrict__ pred,
                          const float* __restrict__ targ,
                          float* __restrict__ ws, int b) {
  __shared__ float ush[80], vsh[80], wred[3];
  const int tid = threadIdx.x;
  const bool act = tid < 136;
  const int r = act ? (tid >> 1) : 0;
  const int q = tid & 1;
  const int rb = q * 40;               // LDS read base (16B aligned, groups of 40)
  const int j0 = act ? q * 34 : 0;

  const float2* pc = (const float2*)(pred + b * NKP * 2);
  const float2* tc = (const float2*)(targ + b * NKP * 2);
  const float2 xi = pc[r];   // pred point, f-row r
  const float2 yj = tc[r];   // targ point, g-row r

  // Wf row (vs targ points), Wg row (transpose: pred points vs yj)
  const float4 wf0 = make_float4(wcomp(xi, tc[j0+ 0]), wcomp(xi, tc[j0+ 1]), wcomp(xi, tc[j0+ 2]), wcomp(xi, tc[j0+ 3]));
  const float4 wf1 = make_float4(wcomp(xi, tc[j0+ 4]), wcomp(xi, tc[j0+ 5]), wcomp(xi, tc[j0+ 6]), wcomp(xi, tc[j0+ 7]));
  const float4 wf2 = make_float4(wcomp(xi, tc[j0+ 8]), wcomp(xi, tc[j0+ 9]), wcomp(xi, tc[j0+10]), wcomp(xi, tc[j0+11]));
  const float4 wf3 = make_float4(wcomp(xi, tc[j0+12]), wcomp(xi, tc[j0+13]), wcomp(xi, tc[j0+14]), wcomp(xi, tc[j0+15]));
  const float4 wf4 = make_float4(wcomp(xi, tc[j0+16]), wcomp(xi, tc[j0+17]), wcomp(xi, tc[j0+18]), wcomp(xi, tc[j0+19]));
  const float4 wf5 = make_float4(wcomp(xi, tc[j0+20]), wcomp(xi, tc[j0+21]), wcomp(xi, tc[j0+22]), wcomp(xi, tc[j0+23]));
  const float4 wf6 = make_float4(wcomp(xi, tc[j0+24]), wcomp(xi, tc[j0+25]), wcomp(xi, tc[j0+26]), wcomp(xi, tc[j0+27]));
  const float4 wf7 = make_float4(wcomp(xi, tc[j0+28]), wcomp(xi, tc[j0+29]), wcomp(xi, tc[j0+30]), wcomp(xi, tc[j0+31]));
  const float2 wf8 = make_float2(wcomp(xi, tc[j0+32]), wcomp(xi, tc[j0+33]));
  const float4 wg0 = make_float4(wcomp(pc[j0+ 0], yj), wcomp(pc[j0+ 1], yj), wcomp(pc[j0+ 2], yj), wcomp(pc[j0+ 3], yj));
  const float4 wg1 = make_float4(wcomp(pc[j0+ 4], yj), wcomp(pc[j0+ 5], yj), wcomp(pc[j0+ 6], yj), wcomp(pc[j0+ 7], yj));
  const float4 wg2 = make_float4(wcomp(pc[j0+ 8], yj), wcomp(pc[j0+ 9], yj), wcomp(pc[j0+10], yj), wcomp(pc[j0+11], yj));
  const float4 wg3 = make_float4(wcomp(pc[j0+12], yj), wcomp(pc[j0+13], yj), wcomp(pc[j0+14], yj), wcomp(pc[j0+15], yj));
  const float4 wg4 = make_float4(wcomp(pc[j0+16], yj), wcomp(pc[j0+17], yj), wcomp(pc[j0+18], yj), wcomp(pc[j0+19], yj));
  const float4 wg5 = make_float4(wcomp(pc[j0+20], yj), wcomp(pc[j0+21], yj), wcomp(pc[j0+22], yj), wcomp(pc[j0+23], yj));
  const float4 wg6 = make_float4(wcomp(pc[j0+24], yj), wcomp(pc[j0+25], yj), wcomp(pc[j0+26], yj), wcomp(pc[j0+27], yj));
  const float4 wg7 = make_float4(wcomp(pc[j0+28], yj), wcomp(pc[j0+29], yj), wcomp(pc[j0+30], yj), wcomp(pc[j0+31], yj));
  const float2 wg8 = make_float2(wcomp(pc[j0+32], yj), wcomp(pc[j0+33], yj));

  const int wofs = (r < 34) ? r : r + 6;   // padded write offset
  if (tid < 80) vsh[tid] = 1.0f;           // v0 = exp(g0/eps) = 1
  __syncthreads();

#define ACC4(W, G)                                                           \
    s0 = fmaf(W.x, G.x, s0); s1 = fmaf(W.y, G.y, s1);                        \
    s2 = fmaf(W.z, G.z, s2); s3 = fmaf(W.w, G.w, s3);

#define SINK_HALF(SRC, DST, WP, RESULT)                                      \
  {                                                                          \
    const float4* gv = (const float4*)&SRC[rb];                              \
    float4 g0 = gv[0], g1 = gv[1], g2 = gv[2], g3 = gv[3];                   \
    float4 g4 = gv[4], g5 = gv[5], g6 = gv[6], g7 = gv[7];                   \
    float2 g8 = *(const float2*)&SRC[rb + 32];                               \
    float s0 = 0, s1 = 0, s2 = 0, s3 = 0;                                    \
    ACC4(WREG(WP,0), g0) ACC4(WREG(WP,1), g1)                                \
    ACC4(WREG(WP,2), g2) ACC4(WREG(WP,3), g3)                                \
    ACC4(WREG(WP,4), g4) ACC4(WREG(WP,5), g5)                                \
    ACC4(WREG(WP,6), g6) ACC4(WREG(WP,7), g7)                                \
    s0 = fmaf(WREG(WP,8).x, g8.x, s0);                                       \
    s1 = fmaf(WREG(WP,8).y, g8.y, s1);                                       \
    float s = (s0 + s1) + (s2 + s3);                                         \
    s = dpp_xor1_add(s);                                                     \
    RESULT = RCP(s) * 0x1p+40f;                                              \
    if (act && q == 0) DST[wofs] = RESULT;                                   \
  }

  float u = 0.0f;
#pragma unroll 1
  for (int it = 0; it < SK_ITERS; ++it) {
    float vdummy;
    SINK_HALF(vsh, ush, wf, u)       // f-half: u = 2^40 / (W v)
    __syncthreads();
    SINK_HALF(ush, vsh, wg, vdummy)  // g-half: v = 2^40 / (W^T u)
    (void)vdummy;
    __syncthreads();
  }

  // transport cost: cost_b = 2^-40/N * sum_i u_i * sum_j (W_ij C_ij) v_j
  // C_ij recovered from log2(Wf); underflowed W (==0) contributes exactly 0.
#define CT(w, g) ((w) > 0.0f ? (w) * ((WBIAS - L2(w)) * (1.0f / KGF)) * (g) : 0.0f)
#define CACC4(W, G)                                                          \
    c0 += CT(W.x, G.x); c1 += CT(W.y, G.y);                                  \
    c2 += CT(W.z, G.z); c3 += CT(W.w, G.w);

  float local = 0.0f;
  {
    const float4* gv = (const float4*)&vsh[rb];
    float4 g0 = gv[0], g1 = gv[1], g2 = gv[2], g3 = gv[3];
    float4 g4 = gv[4], g5 = gv[5], g6 = gv[6], g7 = gv[7];
    float2 g8 = *(const float2*)&vsh[rb + 32];
    float c0 = 0, c1 = 0, c2 = 0, c3 = 0;
    CACC4(wf0, g0) CACC4(wf1, g1) CACC4(wf2, g2) CACC4(wf3, g3)
    CACC4(wf4, g4) CACC4(wf5, g5) CACC4(wf6, g6) CACC4(wf7, g7)
    c0 += CT(wf8.x, g8.x); c1 += CT(wf8.y, g8.y);
    float sc = (c0 + c1) + (c2 + c3);
    sc = dpp_xor1_add(sc);
    if (act && q == 0) local = sc * u;
  }
  for (int o = 32; o; o >>= 1) local += __shfl_down(local, o);
  if ((tid & 63) == 0) wred[tid >> 6] = local;
  __syncthreads();
  if (tid == 0)
    ws[WS_COST + b] = (wred[0] + wred[1] + wred[2]) * (0x1p-40f / 68.0f);
}

// ---------------------------------------------------------------------------
// BCE: block = one batch x 8-row y-tile x 128-col x-half. Windowed (40-sample)
// per-axis gaussian sums for normalization; gy staged in LDS; gx recomputed.
// ---------------------------------------------------------------------------
__device__ void bce_part(const float* __restrict__ pred,
                         const float* __restrict__ targ,
                         float* __restrict__ ws, int bidx) {
  __shared__ float ls[4][NKP];
  __shared__ __attribute__((aligned(16))) float gyp8[NKP][8];
  __shared__ __attribute__((aligned(16))) float gyt8[NKP][8];
  __shared__ float pxp_s[NKP], pxt_s[NKP];
  __shared__ float sS[2];
  __shared__ float bred[3];

  const int b = bidx >> 6;
  const int t6 = bidx & 63;
  const int y0 = (t6 >> 1) * 8;
  const int xbase = (t6 & 1) * 128;
  const int tid = threadIdx.x;

  // phase 1a: windowed per-(n,axis) gaussian sums (tail < 2e-5 absolute)
  for (int idx = tid; idx < 272; idx += 192) {
    const int n = idx >> 2, slot = idx & 3;          // 0 px,1 py,2 tx,3 ty
    const float* src = (slot < 2) ? pred : targ;
    const float c = src[(b * NKP + n) * 2 + (slot & 1)] * 255.0f;
    int x0 = (int)c - 19;
    x0 = max(0, min(216, x0));
    float g0 = (float)x0 - c, g1 = g0 + 1.0f, g2 = g0 + 2.0f, g3 = g0 + 3.0f;
    float s0 = 0, s1 = 0, s2 = 0, s3 = 0;
#pragma unroll 2
    for (int v = 0; v < 10; ++v) {
      s0 += E2(g0 * g0 * C2X);
      s1 += E2(g1 * g1 * C2X);
      s2 += E2(g2 * g2 * C2X);
      s3 += E2(g3 * g3 * C2X);
      g0 += 4.0f; g1 += 4.0f; g2 += 4.0f; g3 += 4.0f;
    }
    ls[slot][n] = (s0 + s1) + (s2 + s3);
  }
  // phase 1b: stage x-centers and gy tiles
  for (int idx = tid; idx < NKP * 2; idx += 192) {
    const int n = idx >> 1, tsel = idx & 1;
    const float* c = tsel ? targ : pred;
    float v = c[(b * NKP + n) * 2] * 255.0f;
    (tsel ? pxt_s : pxp_s)[n] = v;
  }
  for (int idx = tid; idx < NKP * 16; idx += 192) {
    const int t2 = idx & 1, rr = (idx >> 1) & 7, n = idx >> 4;
    const float* c = t2 ? targ : pred;
    float py = c[(b * NKP + n) * 2 + 1] * 255.0f;
    float dy = (float)(y0 + rr) - py;
    (t2 ? gyt8 : gyp8)[n][rr] = E2(dy * dy * C2X);
  }
  __syncthreads();

  // reduce ls -> S_p, S_t
  if (tid < 64) {
    float sp = ls[0][tid] * ls[1][tid];
    float st = ls[2][tid] * ls[3][tid];
    if (tid < 4) {
      sp += ls[0][64 + tid] * ls[1][64 + tid];
      st += ls[2][64 + tid] * ls[3][64 + tid];
    }
    for (int o = 32; o; o >>= 1) { sp += __shfl_down(sp, o); st += __shfl_down(st, o); }
    if (tid == 0) { sS[0] = sp; sS[1] = st; }
  }
  __syncthreads();

  // phase 2: heatmap accumulation over keypoints (128 x-threads)
  float accp[8] = {0, 0, 0, 0, 0, 0, 0, 0};
  float acct[8] = {0, 0, 0, 0, 0, 0, 0, 0};
  if (tid < 128) {
    const float fx = (float)(xbase + tid);
    for (int n = 0; n < NKP; ++n) {
      float dxp = fx - pxp_s[n];
      float gxp = E2(dxp * dxp * C2X);
      float dxt = fx - pxt_s[n];
      float gxt = E2(dxt * dxt * C2X);
      const float4 gp0 = *(const float4*)&gyp8[n][0];
      const float4 gp1 = *(const float4*)&gyp8[n][4];
      const float4 gt0 = *(const float4*)&gyt8[n][0];
      const float4 gt1 = *(const float4*)&gyt8[n][4];
      accp[0] = fmaf(gp0.x, gxp, accp[0]);
      accp[1] = fmaf(gp0.y, gxp, accp[1]);
      accp[2] = fmaf(gp0.z, gxp, accp[2]);
      accp[3] = fmaf(gp0.w, gxp, accp[3]);
      accp[4] = fmaf(gp1.x, gxp, accp[4]);
      accp[5] = fmaf(gp1.y, gxp, accp[5]);
      accp[6] = fmaf(gp1.z, gxp, accp[6]);
      accp[7] = fmaf(gp1.w, gxp, accp[7]);
      acct[0] = fmaf(gt0.x, gxt, acct[0]);
      acct[1] = fmaf(gt0.y, gxt, acct[1]);
      acct[2] = fmaf(gt0.z, gxt, acct[2]);
      acct[3] = fmaf(gt0.w, gxt, acct[3]);
      acct[4] = fmaf(gt1.x, gxt, acct[4]);
      acct[5] = fmaf(gt1.y, gxt, acct[5]);
      acct[6] = fmaf(gt1.z, gxt, acct[6]);
      acct[7] = fmaf(gt1.w, gxt, acct[7]);
    }
  }

  // phase 3: bce terms (hardware v_log_f32; L2(0)=-inf -> clamp -100 matches ref)
  float local = 0.0f;
  if (tid < 128) {
    const float rsp = 1.0f / (sS[0] + 1e-8f);
    const float rst = 1.0f / sS[1];
#pragma unroll
    for (int rr = 0; rr < 8; ++rr) {
      float p = accp[rr] * rsp;
      float t = acct[rr] * rst;
      float lp = fmaxf(LN2 * L2(p), -100.0f);
      float l1 = fmaxf(LN2 * L2(1.0f - p), -100.0f);
      local += t * lp + (1.0f - t) * l1;
    }
  }
  for (int o = 32; o; o >>= 1) local += __shfl_down(local, o);
  if ((tid & 63) == 0) bred[tid >> 6] = local;
  __syncthreads();
  if (tid == 0)
    ws[WS_BCE0 + bidx] = bred[0] + bred[1] + bred[2];   // plain store
}

// ---------------------------------------------------------------------------
// Fused main kernel: blocks 0..15 sinkhorn, 16..1039 BCE.
// ---------------------------------------------------------------------------
__global__ __launch_bounds__(192, 3) void k_main(const float* __restrict__ pred,
                                                 const float* __restrict__ targ,
                                                 float* __restrict__ ws) {
  if (blockIdx.x < 16)
    sink_part(pred, targ, ws, blockIdx.x);
  else
    bce_part(pred, targ, ws, blockIdx.x - 16);
}

// ---------------------------------------------------------------------------
// Final combine: reduce 1024 bce partials + 16 costs
// ---------------------------------------------------------------------------
__global__ __launch_bounds__(256) void k_final(const float* __restrict__ ws,
                                               float* __restrict__ out) {
  const int tid = threadIdx.x;
  __shared__ float redb[4], redc[4];
  float vb = 0.0f;
#pragma unroll
  for (int i = 0; i < 4; ++i) vb += ws[WS_BCE0 + tid + 256 * i];
  float vc = (tid < NB) ? ws[WS_COST + tid] : 0.0f;
  for (int o = 32; o; o >>= 1) { vb += __shfl_down(vb, o); vc += __shfl_down(vc, o); }
  if ((tid & 63) == 0) { redb[tid >> 6] = vb; redc[tid >> 6] = vc; }
  __syncthreads();
  if (tid == 0) {
    float B = redb[0] + redb[1] + redb[2] + redb[3];
    float C = redc[0] + redc[1] + redc[2] + redc[3];
    out[0] = -B * (1000000.0f / 1048576.0f) + C * (2000.0f / 16.0f);
  }
}

extern "C" void kernel_launch(void* const* d_in, const int* in_sizes, int n_in,
                              void* d_out, int out_size, void* d_ws, size_t ws_size,
                              hipStream_t stream) {
  const float* pred = (const float*)d_in[0];
  const float* targ = (const float*)d_in[1];
  float* ws = (float*)d_ws;
  float* out = (float*)d_out;

  k_main<<<16 + NB * 64, 192, 0, stream>>>(pred, targ, ws);
  k_final<<<1, 256, 0, stream>>>(ws, out);
}